// Round 8
// baseline (303.143 us; speedup 1.0000x reference)
//
#include <hip/hip_runtime.h>
#include <hip/hip_bf16.h>
#include <hip/hip_fp16.h>
#include <math.h>

#define N_NODES 50000
#define N_HYPER 20000
#define N_EDGES_C 1000000
#define N_REL 256
#define DIM 128
#define SEM_DIM 64
#define CAP 128   // max edges per bucket; mean=50, sigma~7 -> ~11 sigma headroom

typedef unsigned int uint;
typedef unsigned short ushort;
typedef _Float16 v2h __attribute__((ext_vector_type(2)));
typedef _Float16 f16x8 __attribute__((ext_vector_type(8)));
typedef float f32x4 __attribute__((ext_vector_type(4)));

#define SC_2L2E 2.8853900817779268f   // 2*log2(e)
#define SC_L2E  1.4426950408889634f   // log2(e)

__device__ inline float half_sum32(float v) {
#pragma unroll
  for (int m = 1; m < 32; m <<= 1) v += __shfl_xor(v, m, 64);
  return v;
}

__device__ inline ushort f16rn(float f) { return __half_as_ushort(__float2half_rn(f)); }
__device__ inline __half2 u2h2(uint u) { return __builtin_bit_cast(__half2, u); }

__device__ inline float fdot2(__half2 a, __half2 b, float c) {
#if __has_builtin(__builtin_amdgcn_fdot2)
  return __builtin_amdgcn_fdot2(__builtin_bit_cast(v2h, a),
                                __builtin_bit_cast(v2h, b), c, false);
#else
  float2 fa = __half22float2(a), fb = __half22float2(b);
  return fmaf(fa.x, fb.x, fmaf(fa.y, fb.y, c));
#endif
}

// transposes: WT_h[c][k] = fp16(W_r[k][c]);  linwT[k][j] = lin_w[j][k]
__global__ __launch_bounds__(256) void k_prep(const float* __restrict__ Wr,
                                              const float* __restrict__ linw,
                                              ushort* __restrict__ WT_h,
                                              float* __restrict__ linwT) {
  int i = blockIdx.x * 256 + threadIdx.x;
  if (i < DIM * DIM) {
    int k = i >> 7, c = i & 127;
    WT_h[c * DIM + k] = f16rn(Wr[i]);
  } else if (i < 2 * DIM * DIM) {
    int j = i - DIM * DIM;
    int r = j >> 7, c2 = j & 127;
    linwT[c2 * DIM + r] = linw[j];
  }
}

// sem_t_h[r][j] = fp16( (sem_b[j] + sum_k emb[r][k]*sem_w[j][k]) * 2log2e )
__global__ __launch_bounds__(128) void k_sem(const float* __restrict__ emb,
                                             const float* __restrict__ sem_w,
                                             const float* __restrict__ sem_b,
                                             ushort* __restrict__ sem_t_h) {
  __shared__ float sW[DIM][SEM_DIM + 1];
  __shared__ float sE[SEM_DIM];
  int t = threadIdx.x;
  for (int i = t; i < DIM * SEM_DIM; i += 128) sW[i / SEM_DIM][i % SEM_DIM] = sem_w[i];
  int r = blockIdx.x;
  if (t < SEM_DIM) sE[t] = emb[r * SEM_DIM + t];
  __syncthreads();
  float acc = sem_b[t];
#pragma unroll 8
  for (int k = 0; k < SEM_DIM; ++k) acc = fmaf(sE[k], sW[t][k], acc);
  sem_t_h[r * DIM + t] = f16rn(acc * SC_2L2E);
}

// C_h[M x 128] = fp16((X @ W) * scale) via MFMA 16x16x32_f16.
// Optionally emits ne_h = fp16(X). LDS XOR-swizzled in 16B chunks (G4).
template <bool EMIT_NE>
__global__ __launch_bounds__(256) void k_mfma(const float* __restrict__ X,
                                              const ushort* __restrict__ WT_h,
                                              ushort* __restrict__ C_h,
                                              ushort* __restrict__ ne_h,
                                              float scale, int M) {
  __shared__ uint sA[64 * 64];    // 64 rows x 128 halfs, swizzled 16B chunks
  __shared__ uint sB[128 * 64];   // 128 cols x 128 halfs (W^T), swizzled
  int t = threadIdx.x;
  int bm = blockIdx.x * 64;
  int rows = min(64, M - bm);
  // stage A (f32 -> fp16), 16B chunks, chunk' = c0 ^ (row & 15)
  for (int ch = t; ch < 64 * 16; ch += 256) {
    int r = ch >> 4, c0 = ch & 15;
    uint4 v = {0u, 0u, 0u, 0u};
    if (r < rows) {
      const float4* gp = (const float4*)(X + (size_t)(bm + r) * DIM + c0 * 8);
      float4 x0 = gp[0], x1 = gp[1];
      v.x = (uint)f16rn(x0.x) | ((uint)f16rn(x0.y) << 16);
      v.y = (uint)f16rn(x0.z) | ((uint)f16rn(x0.w) << 16);
      v.z = (uint)f16rn(x1.x) | ((uint)f16rn(x1.y) << 16);
      v.w = (uint)f16rn(x1.z) | ((uint)f16rn(x1.w) << 16);
    }
    *(uint4*)&sA[r * 64 + ((c0 ^ (r & 15)) << 2)] = v;
  }
  // stage B (already fp16)
  for (int ch = t; ch < 128 * 16; ch += 256) {
    int c = ch >> 4, c0 = ch & 15;
    uint4 v = *(const uint4*)(WT_h + c * DIM + c0 * 8);
    *(uint4*)&sB[c * 64 + ((c0 ^ (c & 15)) << 2)] = v;
  }
  __syncthreads();
  int wid = t >> 6, lane = t & 63;
  int arow = (wid << 4) + (lane & 15);
  int kg = lane >> 4;           // k-group: lane holds k = ks*32 + kg*8 + [0..7]
  int cl = lane & 15;
  f32x4 acc[8];
#pragma unroll
  for (int nt = 0; nt < 8; ++nt) acc[nt] = (f32x4){0.f, 0.f, 0.f, 0.f};
#pragma unroll
  for (int ks = 0; ks < 4; ++ks) {
    int chA = (ks << 2) + kg;   // 16B-chunk index along k
    f16x8 afrag = *(const f16x8*)&sA[arow * 64 + ((chA ^ (arow & 15)) << 2)];
#pragma unroll
    for (int nt = 0; nt < 8; ++nt) {
      int col = (nt << 4) + cl;
      f16x8 bfrag = *(const f16x8*)&sB[col * 64 + ((chA ^ (col & 15)) << 2)];
      acc[nt] = __builtin_amdgcn_mfma_f32_16x16x32_f16(afrag, bfrag, acc[nt], 0, 0, 0);
    }
  }
  // C/D: col = lane&15, row = (lane>>4)*4 + reg
  int rbase = (wid << 4) + (kg << 2);
#pragma unroll
  for (int nt = 0; nt < 8; ++nt) {
#pragma unroll
    for (int r = 0; r < 4; ++r) {
      int row = rbase + r;
      if (row < rows)
        C_h[(size_t)(bm + row) * DIM + (nt << 4) + cl] = f16rn(acc[nt][r] * scale);
    }
  }
  if (EMIT_NE) {
    for (int ch = t; ch < 64 * 16; ch += 256) {
      int r = ch >> 4, c0 = ch & 15;
      if (r < rows) {
        uint4 v = *(uint4*)&sA[r * 64 + ((c0 ^ (r & 15)) << 2)];
        *(uint4*)(ne_h + (size_t)(bm + r) * DIM + c0 * 8) = v;
      }
    }
  }
}

// bucket scatter: pos = cnt[h]++, ed[h*CAP+pos] = node | (rel<<16)
__global__ void k_scatter(const int* __restrict__ sl, int* __restrict__ cnt,
                          uint* __restrict__ ed) {
  int stride = gridDim.x * blockDim.x;
  for (int e = blockIdx.x * blockDim.x + threadIdx.x; e < N_EDGES_C; e += stride) {
    int node = sl[3 * e + 0];
    int h = sl[3 * e + 1];
    int rel = sl[3 * e + 2];
    int pos = atomicAdd(&cnt[h], 1);
    if (pos < CAP) ed[(size_t)h * CAP + pos] = (uint)node | ((uint)rel << 16);
  }
}

// one wave per hyperedge (2/block); 8 groups x 8 lanes; software-pipelined:
// ed word prefetched 2 rounds ahead, node/rel gathers 1 round ahead.
#define NG 8
#define BLK_H 2
__global__ __launch_bounds__(128) void k_agg(
    const ushort* __restrict__ rh_h, const ushort* __restrict__ rt_h,
    const ushort* __restrict__ semt_h, const ushort* __restrict__ ne_h,
    const uint* __restrict__ ed, const int* __restrict__ cnt,
    float* __restrict__ agg) {
  int wave = threadIdx.x >> 6;
  int lane = threadIdx.x & 63;
  int h = blockIdx.x * BLK_H + wave;
  int g = lane >> 3;
  int pos = lane & 7;
  int d0 = pos * 16;
  const uint4* tp = (const uint4*)(rt_h + ((size_t)h << 7) + d0);
  uint4 tba = tp[0], tbb = tp[1];
  __half2 tb0 = u2h2(tba.x), tb1 = u2h2(tba.y), tb2 = u2h2(tba.z), tb3 = u2h2(tba.w);
  __half2 tb4 = u2h2(tbb.x), tb5 = u2h2(tbb.y), tb6 = u2h2(tbb.z), tb7 = u2h2(tbb.w);
  const __half2 one2 = __floats2half2_rn(1.0f, 1.0f);
  const __half2 m2 = __floats2half2_rn(-2.0f, -2.0f);
  size_t base = (size_t)h * CAP;
  int n = min(cnt[h], CAP);
  float l = 0.0f;
  float4 a0 = {0,0,0,0}, a1 = {0,0,0,0}, a2 = {0,0,0,0}, a3 = {0,0,0,0};

  int e = g;
  if (e < n) {
    uint q = ed[base + e];
    int nodeC = (int)(q & 0xffffu), relC = (int)(q >> 16);
    const uint4* hp = (const uint4*)(rh_h + ((size_t)nodeC << 7) + d0);
    const uint4* sp = (const uint4*)(semt_h + ((size_t)relC << 7) + d0);
    const uint4* np = (const uint4*)(ne_h + ((size_t)nodeC << 7) + d0);
    uint4 ha = hp[0], hb = hp[1], sa = sp[0], sb = sp[1], na = np[0], nb = np[1];
    int e1 = e + NG;
    uint q1 = ed[base + min(e1, n - 1)];
    for (;;) {
      bool more = e1 < n;
      // prefetch next round's gathers (issued before compute; latency hidden)
      int node1 = (int)(q1 & 0xffffu), rel1 = (int)(q1 >> 16);
      const uint4* hp1 = (const uint4*)(rh_h + ((size_t)node1 << 7) + d0);
      const uint4* sp1 = (const uint4*)(semt_h + ((size_t)rel1 << 7) + d0);
      const uint4* np1 = (const uint4*)(ne_h + ((size_t)node1 << 7) + d0);
      uint4 pha = hp1[0], phb = hp1[1], psa = sp1[0], psb = sp1[1];
      uint4 pna = np1[0], pnb = np1[1];
      uint q2 = ed[base + min(e1 + NG, n - 1)];
      // compute current
      float da = 0.0f, db = 0.0f;
#define TP(US, UH, TB, ACC)                      \
      {                                          \
        __half2 arg = __hadd2(TB, u2h2(US));     \
        __half2 e2v = h2exp2(arg);               \
        __half2 r2 = h2rcp(__hadd2(e2v, one2));  \
        __half2 t2 = __hfma2(m2, r2, one2);      \
        ACC = fdot2(u2h2(UH), t2, ACC);          \
      }
      TP(sa.x, ha.x, tb0, da) TP(sa.y, ha.y, tb1, db)
      TP(sa.z, ha.z, tb2, da) TP(sa.w, ha.w, tb3, db)
      TP(sb.x, hb.x, tb4, da) TP(sb.y, hb.y, tb5, db)
      TP(sb.z, hb.z, tb6, da) TP(sb.w, hb.w, tb7, db)
#undef TP
      float dot = da + db;   // = score * log2e (rh prescaled)
      dot += __shfl_xor(dot, 1, 64);
      dot += __shfl_xor(dot, 2, 64);
      dot += __shfl_xor(dot, 4, 64);
      float p = exp2f(dot);
      l += p;
      float2 n0 = __half22float2(u2h2(na.x));
      float2 n1 = __half22float2(u2h2(na.y));
      float2 n2 = __half22float2(u2h2(na.z));
      float2 n3 = __half22float2(u2h2(na.w));
      float2 n4 = __half22float2(u2h2(nb.x));
      float2 n5 = __half22float2(u2h2(nb.y));
      float2 n6 = __half22float2(u2h2(nb.z));
      float2 n7 = __half22float2(u2h2(nb.w));
      a0.x = fmaf(p, n0.x, a0.x); a0.y = fmaf(p, n0.y, a0.y);
      a0.z = fmaf(p, n1.x, a0.z); a0.w = fmaf(p, n1.y, a0.w);
      a1.x = fmaf(p, n2.x, a1.x); a1.y = fmaf(p, n2.y, a1.y);
      a1.z = fmaf(p, n3.x, a1.z); a1.w = fmaf(p, n3.y, a1.w);
      a2.x = fmaf(p, n4.x, a2.x); a2.y = fmaf(p, n4.y, a2.y);
      a2.z = fmaf(p, n5.x, a2.z); a2.w = fmaf(p, n5.y, a2.w);
      a3.x = fmaf(p, n6.x, a3.x); a3.y = fmaf(p, n6.y, a3.y);
      a3.z = fmaf(p, n7.x, a3.z); a3.w = fmaf(p, n7.y, a3.w);
      if (!more) break;
      ha = pha; hb = phb; sa = psa; sb = psb; na = pna; nb = pnb;
      q1 = q2; e1 += NG;
    }
  }
  // merge the 8 groups (lane bits 3,4,5)
#pragma unroll
  for (int mo = 8; mo < 64; mo <<= 1) {
    l += __shfl_xor(l, mo, 64);
    a0.x += __shfl_xor(a0.x, mo, 64); a0.y += __shfl_xor(a0.y, mo, 64);
    a0.z += __shfl_xor(a0.z, mo, 64); a0.w += __shfl_xor(a0.w, mo, 64);
    a1.x += __shfl_xor(a1.x, mo, 64); a1.y += __shfl_xor(a1.y, mo, 64);
    a1.z += __shfl_xor(a1.z, mo, 64); a1.w += __shfl_xor(a1.w, mo, 64);
    a2.x += __shfl_xor(a2.x, mo, 64); a2.y += __shfl_xor(a2.y, mo, 64);
    a2.z += __shfl_xor(a2.z, mo, 64); a2.w += __shfl_xor(a2.w, mo, 64);
    a3.x += __shfl_xor(a3.x, mo, 64); a3.y += __shfl_xor(a3.y, mo, 64);
    a3.z += __shfl_xor(a3.z, mo, 64); a3.w += __shfl_xor(a3.w, mo, 64);
  }
  if (g == 0) {
    float inv = (l > 0.0f) ? __builtin_amdgcn_rcpf(l) : 0.0f;
    float4* op = (float4*)&agg[((size_t)h << 7) + d0];
    float4 o0 = {a0.x * inv, a0.y * inv, a0.z * inv, a0.w * inv};
    float4 o1 = {a1.x * inv, a1.y * inv, a1.z * inv, a1.w * inv};
    float4 o2 = {a2.x * inv, a2.y * inv, a2.z * inv, a2.w * inv};
    float4 o3 = {a3.x * inv, a3.y * inv, a3.z * inv, a3.w * inv};
    op[0] = o0; op[1] = o1; op[2] = o2; op[3] = o3;
  }
}

// fused: C = X @ W; out = LN(leakyrelu(C + bias)) * gamma + beta
#define GBM 64
__global__ __launch_bounds__(256) void k_gemm_ln(
    const float* __restrict__ X, const float* __restrict__ W,
    const float* __restrict__ bias, const float* __restrict__ gamma,
    const float* __restrict__ beta, float* __restrict__ out, int M) {
  __shared__ float sX[GBM][DIM];
  int t = threadIdx.x;
  long bm = (long)blockIdx.x * GBM;
  int rows = min(GBM, M - (int)bm);
  {
    const float4* Xv = (const float4*)(X + bm * DIM);
    float4* sXv = (float4*)&sX[0][0];
    int n4 = rows * DIM / 4;
    for (int i = t; i < n4; i += 256) sXv[i] = Xv[i];
  }
  __syncthreads();
  int c = t & 31;
  int r0 = (t >> 5) * 8;
  float acc[8][4] = {};
  for (int k = 0; k < DIM; k += 4) {
    float4 xr[8];
#pragma unroll
    for (int i = 0; i < 8; ++i) xr[i] = *(const float4*)&sX[r0 + i][k];
#pragma unroll
    for (int kk = 0; kk < 4; ++kk) {
      float w0 = W[(k + kk) * DIM + c];
      float w1 = W[(k + kk) * DIM + c + 32];
      float w2 = W[(k + kk) * DIM + c + 64];
      float w3 = W[(k + kk) * DIM + c + 96];
#pragma unroll
      for (int i = 0; i < 8; ++i) {
        float x = (&xr[i].x)[kk];
        acc[i][0] = fmaf(x, w0, acc[i][0]);
        acc[i][1] = fmaf(x, w1, acc[i][1]);
        acc[i][2] = fmaf(x, w2, acc[i][2]);
        acc[i][3] = fmaf(x, w3, acc[i][3]);
      }
    }
  }
  float b0 = bias[c], b1 = bias[c + 32], b2 = bias[c + 64], b3 = bias[c + 96];
  float g0 = gamma[c], g1 = gamma[c + 32], g2 = gamma[c + 64], g3 = gamma[c + 96];
  float e0 = beta[c], e1 = beta[c + 32], e2 = beta[c + 64], e3 = beta[c + 96];
#pragma unroll
  for (int i = 0; i < 8; ++i) {
    float v0 = acc[i][0] + b0, v1 = acc[i][1] + b1;
    float v2 = acc[i][2] + b2, v3 = acc[i][3] + b3;
    v0 = v0 >= 0.0f ? v0 : 0.01f * v0;
    v1 = v1 >= 0.0f ? v1 : 0.01f * v1;
    v2 = v2 >= 0.0f ? v2 : 0.01f * v2;
    v3 = v3 >= 0.0f ? v3 : 0.01f * v3;
    float mu = half_sum32(v0 + v1 + v2 + v3) * (1.0f / 128.0f);
    float d0 = v0 - mu, d1 = v1 - mu, d2 = v2 - mu, d3 = v3 - mu;
    float var = half_sum32(d0 * d0 + d1 * d1 + d2 * d2 + d3 * d3) * (1.0f / 128.0f);
    float inv = rsqrtf(var + 1e-5f);
    int r = r0 + i;
    if (r < rows) {
      float* Or = out + (bm + r) * DIM;
      Or[c] = d0 * inv * g0 + e0;
      Or[c + 32] = d1 * inv * g1 + e1;
      Or[c + 64] = d2 * inv * g2 + e2;
      Or[c + 96] = d3 * inv * g3 + e3;
    }
  }
}

extern "C" void kernel_launch(void* const* d_in, const int* in_sizes, int n_in,
                              void* d_out, int out_size, void* d_ws, size_t ws_size,
                              hipStream_t stream) {
  const float* node_emb = (const float*)d_in[0];
  const float* sem_emb = (const float*)d_in[1];
  const float* hyper_emb = (const float*)d_in[2];
  const float* W_r = (const float*)d_in[3];
  const float* lin_w = (const float*)d_in[4];
  const float* lin_b = (const float*)d_in[5];
  const float* sem_w = (const float*)d_in[6];
  const float* sem_b = (const float*)d_in[7];
  const float* ln_g = (const float*)d_in[8];
  const float* ln_b = (const float*)d_in[9];
  const int* sl = (const int*)d_in[10];
  float* out = (float*)d_out;

  float* ws = (float*)d_ws;
  float* aggb = ws;                           // 2,560,000 f32
  float* linwT = aggb + 2560000;              // 16,384 f32
  int* cnt = (int*)(linwT + 16384);           // 20,000 (+pad to keep 16B align)
  uint* ed = (uint*)(cnt + 20008);            // 2,560,000 u32
  ushort* rt_h = (ushort*)(ed + 2560000);     // 2,560,000 fp16 (prescaled 2log2e)
  ushort* rh_h = rt_h + 2560000;              // 6,400,000 fp16 (prescaled log2e)
  ushort* ne_h = rh_h + 6400000;              // 6,400,000 fp16
  ushort* semt_h = ne_h + 6400000;            // 32,768 fp16 (prescaled 2log2e)
  ushort* WT_h = semt_h + 32768;              // 16,384 fp16 (W_r^T)

  hipMemsetAsync(cnt, 0, sizeof(int) * 20000, stream);
  k_prep<<<(2 * DIM * DIM + 255) / 256, 256, 0, stream>>>(W_r, lin_w, WT_h, linwT);
  k_sem<<<N_REL, 128, 0, stream>>>(sem_emb, sem_w, sem_b, semt_h);
  k_mfma<false><<<(N_HYPER + 63) / 64, 256, 0, stream>>>(hyper_emb, WT_h, rt_h, nullptr, SC_2L2E, N_HYPER);
  k_mfma<true><<<(N_NODES + 63) / 64, 256, 0, stream>>>(node_emb, WT_h, rh_h, ne_h, SC_L2E, N_NODES);
  k_scatter<<<2048, 256, 0, stream>>>(sl, cnt, ed);
  k_agg<<<N_HYPER / BLK_H, 128, 0, stream>>>(rh_h, rt_h, semt_h, ne_h, ed, cnt, aggb);
  k_gemm_ln<<<(N_HYPER + GBM - 1) / GBM, 256, 0, stream>>>(aggb, linwT, lin_b, ln_g, ln_b, out, N_HYPER);
}

// Round 9
// 300.083 us; speedup vs baseline: 1.0102x; 1.0102x over previous
//
#include <hip/hip_runtime.h>
#include <hip/hip_bf16.h>
#include <hip/hip_fp16.h>
#include <math.h>

#define N_NODES 50000
#define N_HYPER 20000
#define N_EDGES_C 1000000
#define N_REL 256
#define DIM 128
#define SEM_DIM 64
#define CAP 128   // max edges per bucket; mean=50, sigma~7 -> ~11 sigma headroom

typedef unsigned int uint;
typedef unsigned short ushort;
typedef _Float16 v2h __attribute__((ext_vector_type(2)));
typedef _Float16 f16x8 __attribute__((ext_vector_type(8)));
typedef float f32x4 __attribute__((ext_vector_type(4)));

#define SC_2L2E 2.8853900817779268f   // 2*log2(e)
#define SC_L2E  1.4426950408889634f   // log2(e)

__device__ inline float wave_sum64(float v) {
#pragma unroll
  for (int m = 1; m < 64; m <<= 1) v += __shfl_xor(v, m, 64);
  return v;
}

__device__ inline ushort f16rn(float f) { return __half_as_ushort(__float2half_rn(f)); }
__device__ inline __half2 u2h2(uint u) { return __builtin_bit_cast(__half2, u); }

__device__ inline float fdot2(__half2 a, __half2 b, float c) {
#if __has_builtin(__builtin_amdgcn_fdot2)
  return __builtin_amdgcn_fdot2(__builtin_bit_cast(v2h, a),
                                __builtin_bit_cast(v2h, b), c, false);
#else
  float2 fa = __half22float2(a), fb = __half22float2(b);
  return fmaf(fa.x, fb.x, fmaf(fa.y, fb.y, c));
#endif
}

// WT_h[c][k] = fp16(W_r[k][c]);  LW_h[j][k] = fp16(lin_w[j][k]) (flat copy)
__global__ __launch_bounds__(256) void k_prep(const float* __restrict__ Wr,
                                              const float* __restrict__ linw,
                                              ushort* __restrict__ WT_h,
                                              ushort* __restrict__ LW_h) {
  int i = blockIdx.x * 256 + threadIdx.x;
  if (i < DIM * DIM) {
    int k = i >> 7, c = i & 127;
    WT_h[c * DIM + k] = f16rn(Wr[i]);
  } else if (i < 2 * DIM * DIM) {
    int j = i - DIM * DIM;
    LW_h[j] = f16rn(linw[j]);
  }
}

// sem_t_h[r][j] = fp16( (sem_b[j] + sum_k emb[r][k]*sem_w[j][k]) * 2log2e )
__global__ __launch_bounds__(128) void k_sem(const float* __restrict__ emb,
                                             const float* __restrict__ sem_w,
                                             const float* __restrict__ sem_b,
                                             ushort* __restrict__ sem_t_h) {
  __shared__ float sW[DIM][SEM_DIM + 1];
  __shared__ float sE[SEM_DIM];
  int t = threadIdx.x;
  for (int i = t; i < DIM * SEM_DIM; i += 128) sW[i / SEM_DIM][i % SEM_DIM] = sem_w[i];
  int r = blockIdx.x;
  if (t < SEM_DIM) sE[t] = emb[r * SEM_DIM + t];
  __syncthreads();
  float acc = sem_b[t];
#pragma unroll 8
  for (int k = 0; k < SEM_DIM; ++k) acc = fmaf(sE[k], sW[t][k], acc);
  sem_t_h[r * DIM + t] = f16rn(acc * SC_2L2E);
}

// C0 = fp16((X @ B0) * scale0); if DUAL also C1 = fp16(X @ B1).
// B operand layout: B[c][k] (row c = output column). MFMA 16x16x32_f16,
// LDS XOR-swizzled 16B chunks.
template <bool DUAL>
__global__ __launch_bounds__(256) void k_mfma(const float* __restrict__ X,
                                              const ushort* __restrict__ B0h,
                                              const ushort* __restrict__ B1h,
                                              ushort* __restrict__ C0,
                                              ushort* __restrict__ C1,
                                              float scale0, int M) {
  __shared__ uint sA[64 * 64];
  __shared__ uint sB0[128 * 64];
  __shared__ uint sB1[DUAL ? 128 * 64 : 4];
  int t = threadIdx.x;
  int bm = blockIdx.x * 64;
  int rows = min(64, M - bm);
  for (int ch = t; ch < 64 * 16; ch += 256) {
    int r = ch >> 4, c0 = ch & 15;
    uint4 v = {0u, 0u, 0u, 0u};
    if (r < rows) {
      const float4* gp = (const float4*)(X + (size_t)(bm + r) * DIM + c0 * 8);
      float4 x0 = gp[0], x1 = gp[1];
      v.x = (uint)f16rn(x0.x) | ((uint)f16rn(x0.y) << 16);
      v.y = (uint)f16rn(x0.z) | ((uint)f16rn(x0.w) << 16);
      v.z = (uint)f16rn(x1.x) | ((uint)f16rn(x1.y) << 16);
      v.w = (uint)f16rn(x1.z) | ((uint)f16rn(x1.w) << 16);
    }
    *(uint4*)&sA[r * 64 + ((c0 ^ (r & 15)) << 2)] = v;
  }
  for (int ch = t; ch < 128 * 16; ch += 256) {
    int c = ch >> 4, c0 = ch & 15;
    uint4 v = *(const uint4*)(B0h + c * DIM + c0 * 8);
    *(uint4*)&sB0[c * 64 + ((c0 ^ (c & 15)) << 2)] = v;
    if (DUAL) {
      uint4 w = *(const uint4*)(B1h + c * DIM + c0 * 8);
      *(uint4*)&sB1[c * 64 + ((c0 ^ (c & 15)) << 2)] = w;
    }
  }
  __syncthreads();
  int wid = t >> 6, lane = t & 63;
  int arow = (wid << 4) + (lane & 15);
  int kg = lane >> 4;
  int cl = lane & 15;
  f32x4 acc0[8], acc1[8];
#pragma unroll
  for (int nt = 0; nt < 8; ++nt) {
    acc0[nt] = (f32x4){0.f, 0.f, 0.f, 0.f};
    if (DUAL) acc1[nt] = (f32x4){0.f, 0.f, 0.f, 0.f};
  }
#pragma unroll
  for (int ks = 0; ks < 4; ++ks) {
    int chA = (ks << 2) + kg;
    f16x8 afrag = *(const f16x8*)&sA[arow * 64 + ((chA ^ (arow & 15)) << 2)];
#pragma unroll
    for (int nt = 0; nt < 8; ++nt) {
      int col = (nt << 4) + cl;
      f16x8 b0 = *(const f16x8*)&sB0[col * 64 + ((chA ^ (col & 15)) << 2)];
      acc0[nt] = __builtin_amdgcn_mfma_f32_16x16x32_f16(afrag, b0, acc0[nt], 0, 0, 0);
      if (DUAL) {
        f16x8 b1 = *(const f16x8*)&sB1[col * 64 + ((chA ^ (col & 15)) << 2)];
        acc1[nt] = __builtin_amdgcn_mfma_f32_16x16x32_f16(afrag, b1, acc1[nt], 0, 0, 0);
      }
    }
  }
  int rbase = (wid << 4) + (kg << 2);
#pragma unroll
  for (int nt = 0; nt < 8; ++nt) {
#pragma unroll
    for (int r = 0; r < 4; ++r) {
      int row = rbase + r;
      if (row < rows) {
        C0[(size_t)(bm + row) * DIM + (nt << 4) + cl] = f16rn(acc0[nt][r] * scale0);
        if (DUAL)
          C1[(size_t)(bm + row) * DIM + (nt << 4) + cl] = f16rn(acc1[nt][r]);
      }
    }
  }
}

// bucket scatter, 4 edges/thread via 3x int4 loads
__global__ __launch_bounds__(256) void k_scatter(const int* __restrict__ sl,
                                                 int* __restrict__ cnt,
                                                 uint* __restrict__ ed) {
  int i = blockIdx.x * 256 + threadIdx.x;
  int e0 = i * 4;
  if (e0 >= N_EDGES_C) return;
  const int4* p = (const int4*)(sl + 3 * e0);
  int4 a = p[0], b = p[1], c = p[2];
  int nd[4] = {a.x, a.w, b.z, c.y};
  int hh[4] = {a.y, b.x, b.w, c.z};
  int rl[4] = {a.z, b.y, c.x, c.w};
#pragma unroll
  for (int j = 0; j < 4; ++j) {
    int pos = atomicAdd(&cnt[hh[j]], 1);
    if (pos < CAP) ed[(size_t)hh[j] * CAP + pos] = (uint)nd[j] | ((uint)rl[j] << 16);
  }
}

// one wave per hyperedge (2/block); 8 groups x 8 lanes; each group owns one
// edge per round, lane owns 16 dims. fp16 gathers (rh, semt, lp), f32 accum.
// lp = node_emb @ lin_w.T pre-applied, so output is the pre-bias final row.
#define NG 8
#define BLK_H 2
__global__ __launch_bounds__(128) void k_agg(
    const ushort* __restrict__ rh_h, const ushort* __restrict__ rt_h,
    const ushort* __restrict__ semt_h, const ushort* __restrict__ lp_h,
    const uint* __restrict__ ed, const int* __restrict__ cnt,
    float* __restrict__ agg) {
  int wave = threadIdx.x >> 6;
  int lane = threadIdx.x & 63;
  int h = blockIdx.x * BLK_H + wave;
  int g = lane >> 3;
  int pos = lane & 7;
  int d0 = pos * 16;
  const uint4* tp = (const uint4*)(rt_h + ((size_t)h << 7) + d0);
  uint4 tba = tp[0], tbb = tp[1];
  __half2 tb0 = u2h2(tba.x), tb1 = u2h2(tba.y), tb2 = u2h2(tba.z), tb3 = u2h2(tba.w);
  __half2 tb4 = u2h2(tbb.x), tb5 = u2h2(tbb.y), tb6 = u2h2(tbb.z), tb7 = u2h2(tbb.w);
  const __half2 one2 = __floats2half2_rn(1.0f, 1.0f);
  const __half2 m2 = __floats2half2_rn(-2.0f, -2.0f);
  size_t base = (size_t)h * CAP;
  int n = min(cnt[h], CAP);
  float l = 0.0f;
  float4 a0 = {0,0,0,0}, a1 = {0,0,0,0}, a2 = {0,0,0,0}, a3 = {0,0,0,0};

  for (int e = g; e < n; e += NG) {
    uint q = ed[base + e];
    int node = (int)(q & 0xffffu);
    int rel = (int)(q >> 16);
    const uint4* hp = (const uint4*)(rh_h + ((size_t)node << 7) + d0);
    const uint4* sp = (const uint4*)(semt_h + ((size_t)rel << 7) + d0);
    const uint4* np = (const uint4*)(lp_h + ((size_t)node << 7) + d0);
    uint4 ha = hp[0], hb = hp[1];
    uint4 sa = sp[0], sb = sp[1];
    uint4 na = np[0], nb = np[1];
    float da = 0.0f, db = 0.0f;
#define TP(US, UH, TB, ACC)                      \
    {                                            \
      __half2 arg = __hadd2(TB, u2h2(US));       \
      __half2 e2v = h2exp2(arg);                 \
      __half2 r2 = h2rcp(__hadd2(e2v, one2));    \
      __half2 t2 = __hfma2(m2, r2, one2);        \
      ACC = fdot2(u2h2(UH), t2, ACC);            \
    }
    TP(sa.x, ha.x, tb0, da) TP(sa.y, ha.y, tb1, db)
    TP(sa.z, ha.z, tb2, da) TP(sa.w, ha.w, tb3, db)
    TP(sb.x, hb.x, tb4, da) TP(sb.y, hb.y, tb5, db)
    TP(sb.z, hb.z, tb6, da) TP(sb.w, hb.w, tb7, db)
#undef TP
    float dot = da + db;   // = score * log2e (rh prescaled)
    dot += __shfl_xor(dot, 1, 64);
    dot += __shfl_xor(dot, 2, 64);
    dot += __shfl_xor(dot, 4, 64);
    float p = exp2f(dot);
    l += p;
    float2 n0 = __half22float2(u2h2(na.x));
    float2 n1 = __half22float2(u2h2(na.y));
    float2 n2 = __half22float2(u2h2(na.z));
    float2 n3 = __half22float2(u2h2(na.w));
    float2 n4 = __half22float2(u2h2(nb.x));
    float2 n5 = __half22float2(u2h2(nb.y));
    float2 n6 = __half22float2(u2h2(nb.z));
    float2 n7 = __half22float2(u2h2(nb.w));
    a0.x = fmaf(p, n0.x, a0.x); a0.y = fmaf(p, n0.y, a0.y);
    a0.z = fmaf(p, n1.x, a0.z); a0.w = fmaf(p, n1.y, a0.w);
    a1.x = fmaf(p, n2.x, a1.x); a1.y = fmaf(p, n2.y, a1.y);
    a1.z = fmaf(p, n3.x, a1.z); a1.w = fmaf(p, n3.y, a1.w);
    a2.x = fmaf(p, n4.x, a2.x); a2.y = fmaf(p, n4.y, a2.y);
    a2.z = fmaf(p, n5.x, a2.z); a2.w = fmaf(p, n5.y, a2.w);
    a3.x = fmaf(p, n6.x, a3.x); a3.y = fmaf(p, n6.y, a3.y);
    a3.z = fmaf(p, n7.x, a3.z); a3.w = fmaf(p, n7.y, a3.w);
  }
#pragma unroll
  for (int mo = 8; mo < 64; mo <<= 1) {
    l += __shfl_xor(l, mo, 64);
    a0.x += __shfl_xor(a0.x, mo, 64); a0.y += __shfl_xor(a0.y, mo, 64);
    a0.z += __shfl_xor(a0.z, mo, 64); a0.w += __shfl_xor(a0.w, mo, 64);
    a1.x += __shfl_xor(a1.x, mo, 64); a1.y += __shfl_xor(a1.y, mo, 64);
    a1.z += __shfl_xor(a1.z, mo, 64); a1.w += __shfl_xor(a1.w, mo, 64);
    a2.x += __shfl_xor(a2.x, mo, 64); a2.y += __shfl_xor(a2.y, mo, 64);
    a2.z += __shfl_xor(a2.z, mo, 64); a2.w += __shfl_xor(a2.w, mo, 64);
    a3.x += __shfl_xor(a3.x, mo, 64); a3.y += __shfl_xor(a3.y, mo, 64);
    a3.z += __shfl_xor(a3.z, mo, 64); a3.w += __shfl_xor(a3.w, mo, 64);
  }
  if (g == 0) {
    float inv = (l > 0.0f) ? __builtin_amdgcn_rcpf(l) : 0.0f;
    float4* op = (float4*)&agg[((size_t)h << 7) + d0];
    float4 o0 = {a0.x * inv, a0.y * inv, a0.z * inv, a0.w * inv};
    float4 o1 = {a1.x * inv, a1.y * inv, a1.z * inv, a1.w * inv};
    float4 o2 = {a2.x * inv, a2.y * inv, a2.z * inv, a2.w * inv};
    float4 o3 = {a3.x * inv, a3.y * inv, a3.z * inv, a3.w * inv};
    op[0] = o0; op[1] = o1; op[2] = o2; op[3] = o3;
  }
}

// out = LN(leakyrelu(tmp + bias)) * gamma + beta, one wave per row
__global__ __launch_bounds__(256) void k_ln(const float* __restrict__ tmp,
                                            const float* __restrict__ bias,
                                            const float* __restrict__ gamma,
                                            const float* __restrict__ beta,
                                            float* __restrict__ out) {
  int wave = threadIdx.x >> 6, lane = threadIdx.x & 63;
  int row = blockIdx.x * 4 + wave;
  int d = lane * 2;
  float2 v = *(const float2*)&tmp[(size_t)row * DIM + d];
  float2 b = *(const float2*)&bias[d];
  v.x += b.x; v.y += b.y;
  v.x = v.x >= 0.0f ? v.x : 0.01f * v.x;
  v.y = v.y >= 0.0f ? v.y : 0.01f * v.y;
  float mu = wave_sum64(v.x + v.y) * (1.0f / 128.0f);
  float dx = v.x - mu, dy = v.y - mu;
  float var = wave_sum64(dx * dx + dy * dy) * (1.0f / 128.0f);
  float inv = rsqrtf(var + 1e-5f);
  float2 g = *(const float2*)&gamma[d];
  float2 be = *(const float2*)&beta[d];
  float2 o;
  o.x = dx * inv * g.x + be.x;
  o.y = dy * inv * g.y + be.y;
  *(float2*)&out[(size_t)row * DIM + d] = o;
}

extern "C" void kernel_launch(void* const* d_in, const int* in_sizes, int n_in,
                              void* d_out, int out_size, void* d_ws, size_t ws_size,
                              hipStream_t stream) {
  const float* node_emb = (const float*)d_in[0];
  const float* sem_emb = (const float*)d_in[1];
  const float* hyper_emb = (const float*)d_in[2];
  const float* W_r = (const float*)d_in[3];
  const float* lin_w = (const float*)d_in[4];
  const float* lin_b = (const float*)d_in[5];
  const float* sem_w = (const float*)d_in[6];
  const float* sem_b = (const float*)d_in[7];
  const float* ln_g = (const float*)d_in[8];
  const float* ln_b = (const float*)d_in[9];
  const int* sl = (const int*)d_in[10];
  float* out = (float*)d_out;

  float* ws = (float*)d_ws;
  float* aggb = ws;                           // 2,560,000 f32
  int* cnt = (int*)(aggb + 2560000);          // 20,008 ints (16B-align kept)
  uint* ed = (uint*)(cnt + 20008);            // 2,560,000 u32
  ushort* rt_h = (ushort*)(ed + 2560000);     // 2,560,000 fp16 (prescaled 2log2e)
  ushort* rh_h = rt_h + 2560000;              // 6,400,000 fp16 (prescaled log2e)
  ushort* lp_h = rh_h + 6400000;              // 6,400,000 fp16 (node_emb @ lin_w.T)
  ushort* semt_h = lp_h + 6400000;            // 32,768 fp16 (prescaled 2log2e)
  ushort* WT_h = semt_h + 32768;              // 16,384 fp16 (W_r^T)
  ushort* LW_h = WT_h + 16384;                // 16,384 fp16 (lin_w flat)

  hipMemsetAsync(cnt, 0, sizeof(int) * 20000, stream);
  k_prep<<<(2 * DIM * DIM + 255) / 256, 256, 0, stream>>>(W_r, lin_w, WT_h, LW_h);
  k_sem<<<N_REL, 128, 0, stream>>>(sem_emb, sem_w, sem_b, semt_h);
  k_mfma<false><<<(N_HYPER + 63) / 64, 256, 0, stream>>>(
      hyper_emb, WT_h, nullptr, rt_h, nullptr, SC_2L2E, N_HYPER);
  k_mfma<true><<<(N_NODES + 63) / 64, 256, 0, stream>>>(
      node_emb, WT_h, LW_h, rh_h, lp_h, SC_L2E, N_NODES);
  k_scatter<<<(N_EDGES_C / 4 + 255) / 256, 256, 0, stream>>>(sl, cnt, ed);
  k_agg<<<N_HYPER / BLK_H, 128, 0, stream>>>(rh_h, rt_h, semt_h, lp_h, ed, cnt, aggb);
  k_ln<<<N_HYPER / 4, 256, 0, stream>>>(aggb, lin_b, ln_g, ln_b, out);
}

// Round 10
// 255.941 us; speedup vs baseline: 1.1844x; 1.1725x over previous
//
#include <hip/hip_runtime.h>
#include <hip/hip_bf16.h>
#include <hip/hip_fp16.h>
#include <math.h>

#define N_NODES 50000
#define N_HYPER 20000
#define N_EDGES_C 1000000
#define N_REL 256
#define DIM 128
#define SEM_DIM 64
#define CAP 128   // max edges per bucket; mean=50, sigma~7 -> ~11 sigma headroom

typedef unsigned int uint;
typedef unsigned short ushort;
typedef _Float16 v2h __attribute__((ext_vector_type(2)));
typedef _Float16 f16x8 __attribute__((ext_vector_type(8)));
typedef float f32x4 __attribute__((ext_vector_type(4)));

#define SC_2L2E 2.8853900817779268f   // 2*log2(e)
#define SC_L2E  1.4426950408889634f   // log2(e)

__device__ inline ushort f16rn(float f) { return __half_as_ushort(__float2half_rn(f)); }
__device__ inline __half2 u2h2(uint u) { return __builtin_bit_cast(__half2, u); }

__device__ inline float fdot2(__half2 a, __half2 b, float c) {
#if __has_builtin(__builtin_amdgcn_fdot2)
  return __builtin_amdgcn_fdot2(__builtin_bit_cast(v2h, a),
                                __builtin_bit_cast(v2h, b), c, false);
#else
  float2 fa = __half22float2(a), fb = __half22float2(b);
  return fmaf(fa.x, fb.x, fmaf(fa.y, fb.y, c));
#endif
}

// WT_h[c][k] = fp16(W_r[k][c]);  LW_h[j][k] = fp16(lin_w[j][k]) (flat copy)
__global__ __launch_bounds__(256) void k_prep(const float* __restrict__ Wr,
                                              const float* __restrict__ linw,
                                              ushort* __restrict__ WT_h,
                                              ushort* __restrict__ LW_h) {
  int i = blockIdx.x * 256 + threadIdx.x;
  if (i < DIM * DIM) {
    int k = i >> 7, c = i & 127;
    WT_h[c * DIM + k] = f16rn(Wr[i]);
  } else if (i < 2 * DIM * DIM) {
    int j = i - DIM * DIM;
    LW_h[j] = f16rn(linw[j]);
  }
}

// sem_t_h[r][j] = fp16( (sem_b[j] + sum_k emb[r][k]*sem_w[j][k]) * 2log2e )
__global__ __launch_bounds__(128) void k_sem(const float* __restrict__ emb,
                                             const float* __restrict__ sem_w,
                                             const float* __restrict__ sem_b,
                                             ushort* __restrict__ sem_t_h) {
  __shared__ float sW[DIM][SEM_DIM + 1];
  __shared__ float sE[SEM_DIM];
  int t = threadIdx.x;
  for (int i = t; i < DIM * SEM_DIM; i += 128) sW[i / SEM_DIM][i % SEM_DIM] = sem_w[i];
  int r = blockIdx.x;
  if (t < SEM_DIM) sE[t] = emb[r * SEM_DIM + t];
  __syncthreads();
  float acc = sem_b[t];
#pragma unroll 8
  for (int k = 0; k < SEM_DIM; ++k) acc = fmaf(sE[k], sW[t][k], acc);
  sem_t_h[r * DIM + t] = f16rn(acc * SC_2L2E);
}

// C0 = fp16((X @ B0) * scale0); optionally ne = fp16(X) from the LDS copy.
// B layout: B[c][k] (row c = output col). MFMA 16x16x32_f16, XOR-swizzled LDS.
template <bool EMIT_NE>
__global__ __launch_bounds__(256) void k_mfma(const float* __restrict__ X,
                                              const ushort* __restrict__ B0h,
                                              ushort* __restrict__ C0,
                                              ushort* __restrict__ ne_h,
                                              float scale0, int M) {
  __shared__ uint sA[64 * 64];     // 64 rows x 128 halfs
  __shared__ uint sB0[128 * 64];   // 128 cols x 128 halfs
  int t = threadIdx.x;
  int bm = blockIdx.x * 64;
  int rows = min(64, M - bm);
  for (int ch = t; ch < 64 * 16; ch += 256) {
    int r = ch >> 4, c0 = ch & 15;
    uint4 v = {0u, 0u, 0u, 0u};
    if (r < rows) {
      const float4* gp = (const float4*)(X + (size_t)(bm + r) * DIM + c0 * 8);
      float4 x0 = gp[0], x1 = gp[1];
      v.x = (uint)f16rn(x0.x) | ((uint)f16rn(x0.y) << 16);
      v.y = (uint)f16rn(x0.z) | ((uint)f16rn(x0.w) << 16);
      v.z = (uint)f16rn(x1.x) | ((uint)f16rn(x1.y) << 16);
      v.w = (uint)f16rn(x1.z) | ((uint)f16rn(x1.w) << 16);
    }
    *(uint4*)&sA[r * 64 + ((c0 ^ (r & 15)) << 2)] = v;
  }
  for (int ch = t; ch < 128 * 16; ch += 256) {
    int c = ch >> 4, c0 = ch & 15;
    uint4 v = *(const uint4*)(B0h + c * DIM + c0 * 8);
    *(uint4*)&sB0[c * 64 + ((c0 ^ (c & 15)) << 2)] = v;
  }
  __syncthreads();
  int wid = t >> 6, lane = t & 63;
  int arow = (wid << 4) + (lane & 15);
  int kg = lane >> 4;
  int cl = lane & 15;
  f32x4 acc0[8];
#pragma unroll
  for (int nt = 0; nt < 8; ++nt) acc0[nt] = (f32x4){0.f, 0.f, 0.f, 0.f};
#pragma unroll
  for (int ks = 0; ks < 4; ++ks) {
    int chA = (ks << 2) + kg;
    f16x8 afrag = *(const f16x8*)&sA[arow * 64 + ((chA ^ (arow & 15)) << 2)];
#pragma unroll
    for (int nt = 0; nt < 8; ++nt) {
      int col = (nt << 4) + cl;
      f16x8 b0 = *(const f16x8*)&sB0[col * 64 + ((chA ^ (col & 15)) << 2)];
      acc0[nt] = __builtin_amdgcn_mfma_f32_16x16x32_f16(afrag, b0, acc0[nt], 0, 0, 0);
    }
  }
  int rbase = (wid << 4) + (kg << 2);
#pragma unroll
  for (int nt = 0; nt < 8; ++nt) {
#pragma unroll
    for (int r = 0; r < 4; ++r) {
      int row = rbase + r;
      if (row < rows)
        C0[(size_t)(bm + row) * DIM + (nt << 4) + cl] = f16rn(acc0[nt][r] * scale0);
    }
  }
  if (EMIT_NE) {
    for (int ch = t; ch < 64 * 16; ch += 256) {
      int r = ch >> 4, c0 = ch & 15;
      if (r < rows) {
        uint4 v = *(uint4*)&sA[r * 64 + ((c0 ^ (r & 15)) << 2)];
        *(uint4*)(ne_h + (size_t)(bm + r) * DIM + c0 * 8) = v;
      }
    }
  }
}

// bucket scatter, 4 edges/thread via 3x int4 loads
__global__ __launch_bounds__(256) void k_scatter(const int* __restrict__ sl,
                                                 int* __restrict__ cnt,
                                                 uint* __restrict__ ed) {
  int i = blockIdx.x * 256 + threadIdx.x;
  int e0 = i * 4;
  if (e0 >= N_EDGES_C) return;
  const int4* p = (const int4*)(sl + 3 * e0);
  int4 a = p[0], b = p[1], c = p[2];
  int nd[4] = {a.x, a.w, b.z, c.y};
  int hh[4] = {a.y, b.x, b.w, c.z};
  int rl[4] = {a.z, b.y, c.x, c.w};
#pragma unroll
  for (int j = 0; j < 4; ++j) {
    int pos = atomicAdd(&cnt[hh[j]], 1);
    if (pos < CAP) ed[(size_t)hh[j] * CAP + pos] = (uint)nd[j] | ((uint)rl[j] << 16);
  }
}

// one wave per hyperedge (2/block); 8 groups x 8 lanes; group owns one edge
// per round, lane owns 16 dims. fp16 gathers (rh, semt, ne), f32 accum,
// no softmax-max (|score| << 88). Output agg as fp16 (feeds MFMA final).
#define NG 8
#define BLK_H 2
__global__ __launch_bounds__(128) void k_agg(
    const ushort* __restrict__ rh_h, const ushort* __restrict__ rt_h,
    const ushort* __restrict__ semt_h, const ushort* __restrict__ ne_h,
    const uint* __restrict__ ed, const int* __restrict__ cnt,
    ushort* __restrict__ agg_h) {
  int wave = threadIdx.x >> 6;
  int lane = threadIdx.x & 63;
  int h = blockIdx.x * BLK_H + wave;
  int g = lane >> 3;
  int pos = lane & 7;
  int d0 = pos * 16;
  const uint4* tp = (const uint4*)(rt_h + ((size_t)h << 7) + d0);
  uint4 tba = tp[0], tbb = tp[1];
  __half2 tb0 = u2h2(tba.x), tb1 = u2h2(tba.y), tb2 = u2h2(tba.z), tb3 = u2h2(tba.w);
  __half2 tb4 = u2h2(tbb.x), tb5 = u2h2(tbb.y), tb6 = u2h2(tbb.z), tb7 = u2h2(tbb.w);
  const __half2 one2 = __floats2half2_rn(1.0f, 1.0f);
  const __half2 m2 = __floats2half2_rn(-2.0f, -2.0f);
  size_t base = (size_t)h * CAP;
  int n = min(cnt[h], CAP);
  float l = 0.0f;
  float4 a0 = {0,0,0,0}, a1 = {0,0,0,0}, a2 = {0,0,0,0}, a3 = {0,0,0,0};

  for (int e = g; e < n; e += NG) {
    uint q = ed[base + e];
    int node = (int)(q & 0xffffu);
    int rel = (int)(q >> 16);
    const uint4* hp = (const uint4*)(rh_h + ((size_t)node << 7) + d0);
    const uint4* sp = (const uint4*)(semt_h + ((size_t)rel << 7) + d0);
    const uint4* np = (const uint4*)(ne_h + ((size_t)node << 7) + d0);
    uint4 ha = hp[0], hb = hp[1];
    uint4 sa = sp[0], sb = sp[1];
    uint4 na = np[0], nb = np[1];
    float da = 0.0f, db = 0.0f;
#define TP(US, UH, TB, ACC)                      \
    {                                            \
      __half2 arg = __hadd2(TB, u2h2(US));       \
      __half2 e2v = h2exp2(arg);                 \
      __half2 r2 = h2rcp(__hadd2(e2v, one2));    \
      __half2 t2 = __hfma2(m2, r2, one2);        \
      ACC = fdot2(u2h2(UH), t2, ACC);            \
    }
    TP(sa.x, ha.x, tb0, da) TP(sa.y, ha.y, tb1, db)
    TP(sa.z, ha.z, tb2, da) TP(sa.w, ha.w, tb3, db)
    TP(sb.x, hb.x, tb4, da) TP(sb.y, hb.y, tb5, db)
    TP(sb.z, hb.z, tb6, da) TP(sb.w, hb.w, tb7, db)
#undef TP
    float dot = da + db;   // = score * log2e (rh prescaled)
    dot += __shfl_xor(dot, 1, 64);
    dot += __shfl_xor(dot, 2, 64);
    dot += __shfl_xor(dot, 4, 64);
    float p = exp2f(dot);
    l += p;
    float2 n0 = __half22float2(u2h2(na.x));
    float2 n1 = __half22float2(u2h2(na.y));
    float2 n2 = __half22float2(u2h2(na.z));
    float2 n3 = __half22float2(u2h2(na.w));
    float2 n4 = __half22float2(u2h2(nb.x));
    float2 n5 = __half22float2(u2h2(nb.y));
    float2 n6 = __half22float2(u2h2(nb.z));
    float2 n7 = __half22float2(u2h2(nb.w));
    a0.x = fmaf(p, n0.x, a0.x); a0.y = fmaf(p, n0.y, a0.y);
    a0.z = fmaf(p, n1.x, a0.z); a0.w = fmaf(p, n1.y, a0.w);
    a1.x = fmaf(p, n2.x, a1.x); a1.y = fmaf(p, n2.y, a1.y);
    a1.z = fmaf(p, n3.x, a1.z); a1.w = fmaf(p, n3.y, a1.w);
    a2.x = fmaf(p, n4.x, a2.x); a2.y = fmaf(p, n4.y, a2.y);
    a2.z = fmaf(p, n5.x, a2.z); a2.w = fmaf(p, n5.y, a2.w);
    a3.x = fmaf(p, n6.x, a3.x); a3.y = fmaf(p, n6.y, a3.y);
    a3.z = fmaf(p, n7.x, a3.z); a3.w = fmaf(p, n7.y, a3.w);
  }
#pragma unroll
  for (int mo = 8; mo < 64; mo <<= 1) {
    l += __shfl_xor(l, mo, 64);
    a0.x += __shfl_xor(a0.x, mo, 64); a0.y += __shfl_xor(a0.y, mo, 64);
    a0.z += __shfl_xor(a0.z, mo, 64); a0.w += __shfl_xor(a0.w, mo, 64);
    a1.x += __shfl_xor(a1.x, mo, 64); a1.y += __shfl_xor(a1.y, mo, 64);
    a1.z += __shfl_xor(a1.z, mo, 64); a1.w += __shfl_xor(a1.w, mo, 64);
    a2.x += __shfl_xor(a2.x, mo, 64); a2.y += __shfl_xor(a2.y, mo, 64);
    a2.z += __shfl_xor(a2.z, mo, 64); a2.w += __shfl_xor(a2.w, mo, 64);
    a3.x += __shfl_xor(a3.x, mo, 64); a3.y += __shfl_xor(a3.y, mo, 64);
    a3.z += __shfl_xor(a3.z, mo, 64); a3.w += __shfl_xor(a3.w, mo, 64);
  }
  if (g == 0) {
    float inv = (l > 0.0f) ? __builtin_amdgcn_rcpf(l) : 0.0f;
    uint4 w0, w1;
    w0.x = (uint)f16rn(a0.x * inv) | ((uint)f16rn(a0.y * inv) << 16);
    w0.y = (uint)f16rn(a0.z * inv) | ((uint)f16rn(a0.w * inv) << 16);
    w0.z = (uint)f16rn(a1.x * inv) | ((uint)f16rn(a1.y * inv) << 16);
    w0.w = (uint)f16rn(a1.z * inv) | ((uint)f16rn(a1.w * inv) << 16);
    w1.x = (uint)f16rn(a2.x * inv) | ((uint)f16rn(a2.y * inv) << 16);
    w1.y = (uint)f16rn(a2.z * inv) | ((uint)f16rn(a2.w * inv) << 16);
    w1.z = (uint)f16rn(a3.x * inv) | ((uint)f16rn(a3.y * inv) << 16);
    w1.w = (uint)f16rn(a3.z * inv) | ((uint)f16rn(a3.w * inv) << 16);
    *(uint4*)(agg_h + ((size_t)h << 7) + d0) = w0;
    *(uint4*)(agg_h + ((size_t)h << 7) + d0 + 8) = w1;
  }
}

// final: C = agg @ lin_w.T (MFMA, fp16 inputs), then fused
// out = LN(leakyrelu(C + bias)) * gamma + beta.  Row stats via 16-lane shuffle
// over the C-fragment layout (row r's 128 cols live in the 16 lanes sharing kg).
__global__ __launch_bounds__(256) void k_mfma_ln(
    const ushort* __restrict__ Ah, const ushort* __restrict__ LWh,
    const float* __restrict__ bias, const float* __restrict__ gamma,
    const float* __restrict__ beta, float* __restrict__ out, int M) {
  __shared__ uint sA[64 * 64];
  __shared__ uint sB0[128 * 64];
  int t = threadIdx.x;
  int bm = blockIdx.x * 64;
  int rows = min(64, M - bm);
  for (int ch = t; ch < 64 * 16; ch += 256) {
    int r = ch >> 4, c0 = ch & 15;
    uint4 v = {0u, 0u, 0u, 0u};
    if (r < rows) v = *(const uint4*)(Ah + (size_t)(bm + r) * DIM + c0 * 8);
    *(uint4*)&sA[r * 64 + ((c0 ^ (r & 15)) << 2)] = v;
  }
  for (int ch = t; ch < 128 * 16; ch += 256) {
    int c = ch >> 4, c0 = ch & 15;
    uint4 v = *(const uint4*)(LWh + c * DIM + c0 * 8);
    *(uint4*)&sB0[c * 64 + ((c0 ^ (c & 15)) << 2)] = v;
  }
  __syncthreads();
  int wid = t >> 6, lane = t & 63;
  int arow = (wid << 4) + (lane & 15);
  int kg = lane >> 4;
  int cl = lane & 15;
  f32x4 acc0[8];
#pragma unroll
  for (int nt = 0; nt < 8; ++nt) acc0[nt] = (f32x4){0.f, 0.f, 0.f, 0.f};
#pragma unroll
  for (int ks = 0; ks < 4; ++ks) {
    int chA = (ks << 2) + kg;
    f16x8 afrag = *(const f16x8*)&sA[arow * 64 + ((chA ^ (arow & 15)) << 2)];
#pragma unroll
    for (int nt = 0; nt < 8; ++nt) {
      int col = (nt << 4) + cl;
      f16x8 b0 = *(const f16x8*)&sB0[col * 64 + ((chA ^ (col & 15)) << 2)];
      acc0[nt] = __builtin_amdgcn_mfma_f32_16x16x32_f16(afrag, b0, acc0[nt], 0, 0, 0);
    }
  }
  // epilogue: bias + leaky, then per-row LN across the 16-lane kg-group
  float bv[8], gv[8], ev[8];
#pragma unroll
  for (int nt = 0; nt < 8; ++nt) {
    int col = (nt << 4) + cl;
    bv[nt] = bias[col]; gv[nt] = gamma[col]; ev[nt] = beta[col];
  }
  int rbase = (wid << 4) + (kg << 2);
#pragma unroll
  for (int r = 0; r < 4; ++r) {
    float s = 0.f, q = 0.f;
#pragma unroll
    for (int nt = 0; nt < 8; ++nt) {
      float x = acc0[nt][r] + bv[nt];
      x = x >= 0.0f ? x : 0.01f * x;
      acc0[nt][r] = x;
      s += x; q += x * x;
    }
#pragma unroll
    for (int mo = 1; mo < 16; mo <<= 1) {
      s += __shfl_xor(s, mo, 64);
      q += __shfl_xor(q, mo, 64);
    }
    float mu = s * (1.0f / 128.0f);
    float var = q * (1.0f / 128.0f) - mu * mu;
    float inv = rsqrtf(var + 1e-5f);
    int row = rbase + r;
    if (row < rows) {
      float* Or = out + (size_t)(bm + row) * DIM;
#pragma unroll
      for (int nt = 0; nt < 8; ++nt)
        Or[(nt << 4) + cl] = (acc0[nt][r] - mu) * inv * gv[nt] + ev[nt];
    }
  }
}

extern "C" void kernel_launch(void* const* d_in, const int* in_sizes, int n_in,
                              void* d_out, int out_size, void* d_ws, size_t ws_size,
                              hipStream_t stream) {
  const float* node_emb = (const float*)d_in[0];
  const float* sem_emb = (const float*)d_in[1];
  const float* hyper_emb = (const float*)d_in[2];
  const float* W_r = (const float*)d_in[3];
  const float* lin_w = (const float*)d_in[4];
  const float* lin_b = (const float*)d_in[5];
  const float* sem_w = (const float*)d_in[6];
  const float* sem_b = (const float*)d_in[7];
  const float* ln_g = (const float*)d_in[8];
  const float* ln_b = (const float*)d_in[9];
  const int* sl = (const int*)d_in[10];
  float* out = (float*)d_out;

  // all segments 256-byte aligned
  char* ws = (char*)d_ws;
  ushort* agg_h = (ushort*)ws;                    // 2,560,000 halfs (5,120,000 B)
  int* cnt = (int*)(ws + 5120000);                // 20,480 ints (81,920 B)
  uint* ed = (uint*)(ws + 5201920);               // 2,560,000 u32 (10,240,000 B)
  ushort* rt_h = (ushort*)(ws + 15441920);        // 2,560,000 halfs (5,120,000 B)
  ushort* rh_h = (ushort*)(ws + 20561920);        // 6,400,000 halfs (12,800,000 B)
  ushort* ne_h = (ushort*)(ws + 33361920);        // 6,400,000 halfs (12,800,000 B)
  ushort* semt_h = (ushort*)(ws + 46161920);      // 32,768 halfs (65,536 B)
  ushort* WT_h = (ushort*)(ws + 46227456);        // 16,384 halfs (32,768 B)
  ushort* LW_h = (ushort*)(ws + 46260224);        // 16,384 halfs (32,768 B)

  hipMemsetAsync(cnt, 0, sizeof(int) * 20480, stream);
  k_prep<<<(2 * DIM * DIM + 255) / 256, 256, 0, stream>>>(W_r, lin_w, WT_h, LW_h);
  k_sem<<<N_REL, 128, 0, stream>>>(sem_emb, sem_w, sem_b, semt_h);
  k_mfma<false><<<(N_HYPER + 63) / 64, 256, 0, stream>>>(
      hyper_emb, WT_h, rt_h, nullptr, SC_2L2E, N_HYPER);
  k_mfma<true><<<(N_NODES + 63) / 64, 256, 0, stream>>>(
      node_emb, WT_h, rh_h, ne_h, SC_L2E, N_NODES);
  k_scatter<<<(N_EDGES_C / 4 + 255) / 256, 256, 0, stream>>>(sl, cnt, ed);
  k_agg<<<N_HYPER / BLK_H, 128, 0, stream>>>(rh_h, rt_h, semt_h, ne_h, ed, cnt, agg_h);
  k_mfma_ln<<<(N_HYPER + 63) / 64, 256, 0, stream>>>(
      agg_h, LW_h, lin_b, ln_g, ln_b, out, N_HYPER);
}

// Round 11
// 248.089 us; speedup vs baseline: 1.2219x; 1.0317x over previous
//
#include <hip/hip_runtime.h>
#include <hip/hip_bf16.h>
#include <hip/hip_fp16.h>
#include <math.h>

#define N_NODES 50000
#define N_HYPER 20000
#define N_EDGES_C 1000000
#define N_REL 256
#define DIM 128
#define SEM_DIM 64
#define CAP 128   // max edges per bucket; mean=50, sigma~7 -> ~11 sigma headroom

typedef unsigned int uint;
typedef unsigned short ushort;
typedef _Float16 v2h __attribute__((ext_vector_type(2)));
typedef _Float16 f16x8 __attribute__((ext_vector_type(8)));
typedef float f32x4 __attribute__((ext_vector_type(4)));

#define SC_2L2E 2.8853900817779268f   // 2*log2(e)
#define SC_L2E  1.4426950408889634f   // log2(e)

__device__ inline ushort f16rn(float f) { return __half_as_ushort(__float2half_rn(f)); }
__device__ inline __half2 u2h2(uint u) { return __builtin_bit_cast(__half2, u); }

__device__ inline float fdot2(__half2 a, __half2 b, float c) {
#if __has_builtin(__builtin_amdgcn_fdot2)
  return __builtin_amdgcn_fdot2(__builtin_bit_cast(v2h, a),
                                __builtin_bit_cast(v2h, b), c, false);
#else
  float2 fa = __half22float2(a), fb = __half22float2(b);
  return fmaf(fa.x, fb.x, fmaf(fa.y, fb.y, c));
#endif
}

__device__ inline uint getq(uint qv0, uint qv1, int src) {
  uint a = __shfl(qv0, src & 63, 64);
  uint b = __shfl(qv1, src & 63, 64);
  return (src < 64) ? a : b;
}

// fused: blocks [0,256) = sem_t; blocks [256,512) = weight transposes/converts
__global__ __launch_bounds__(128) void k_pre(
    const float* __restrict__ emb, const float* __restrict__ sem_w,
    const float* __restrict__ sem_b, ushort* __restrict__ sem_t_h,
    const float* __restrict__ Wr, const float* __restrict__ linw,
    ushort* __restrict__ WT_h, ushort* __restrict__ LW_h) {
  int b = blockIdx.x;
  int t = threadIdx.x;
  if (b < N_REL) {
    __shared__ float sW[DIM][SEM_DIM + 1];
    __shared__ float sE[SEM_DIM];
    for (int i = t; i < DIM * SEM_DIM; i += 128) sW[i / SEM_DIM][i % SEM_DIM] = sem_w[i];
    if (t < SEM_DIM) sE[t] = emb[b * SEM_DIM + t];
    __syncthreads();
    float acc = sem_b[t];
#pragma unroll 8
    for (int k = 0; k < SEM_DIM; ++k) acc = fmaf(sE[k], sW[t][k], acc);
    sem_t_h[b * DIM + t] = f16rn(acc * SC_2L2E);
  } else {
    int i = (b - N_REL) * 128 + t;
    if (i < DIM * DIM) {
      int k = i >> 7, c = i & 127;
      WT_h[c * DIM + k] = f16rn(Wr[i]);
    } else {
      int j = i - DIM * DIM;
      LW_h[j] = f16rn(linw[j]);
    }
  }
}

// one launch: blocks [0,HB) -> rt_h from hyper_emb; [HB,HB+NB) -> rh_h (+ne_h)
// from node_emb. MFMA 16x16x32_f16, XOR-swizzled LDS.
__global__ __launch_bounds__(256) void k_mfma_all(
    const float* __restrict__ hyper_emb, const float* __restrict__ node_emb,
    const ushort* __restrict__ WT_h, ushort* __restrict__ rt_h,
    ushort* __restrict__ rh_h, ushort* __restrict__ ne_h) {
  const int HB = (N_HYPER + 63) / 64;
  __shared__ uint sA[64 * 64];
  __shared__ uint sB0[128 * 64];
  int b = blockIdx.x;
  bool isH = b < HB;
  const float* X = isH ? hyper_emb : node_emb;
  int bm = (isH ? b : b - HB) * 64;
  int M = isH ? N_HYPER : N_NODES;
  ushort* C0 = isH ? rt_h : rh_h;
  float scale0 = isH ? SC_2L2E : SC_L2E;
  int t = threadIdx.x;
  int rows = min(64, M - bm);
  for (int ch = t; ch < 64 * 16; ch += 256) {
    int r = ch >> 4, c0 = ch & 15;
    uint4 v = {0u, 0u, 0u, 0u};
    if (r < rows) {
      const float4* gp = (const float4*)(X + (size_t)(bm + r) * DIM + c0 * 8);
      float4 x0 = gp[0], x1 = gp[1];
      v.x = (uint)f16rn(x0.x) | ((uint)f16rn(x0.y) << 16);
      v.y = (uint)f16rn(x0.z) | ((uint)f16rn(x0.w) << 16);
      v.z = (uint)f16rn(x1.x) | ((uint)f16rn(x1.y) << 16);
      v.w = (uint)f16rn(x1.z) | ((uint)f16rn(x1.w) << 16);
    }
    *(uint4*)&sA[r * 64 + ((c0 ^ (r & 15)) << 2)] = v;
  }
  for (int ch = t; ch < 128 * 16; ch += 256) {
    int c = ch >> 4, c0 = ch & 15;
    uint4 v = *(const uint4*)(WT_h + c * DIM + c0 * 8);
    *(uint4*)&sB0[c * 64 + ((c0 ^ (c & 15)) << 2)] = v;
  }
  __syncthreads();
  int wid = t >> 6, lane = t & 63;
  int arow = (wid << 4) + (lane & 15);
  int kg = lane >> 4;
  int cl = lane & 15;
  f32x4 acc0[8];
#pragma unroll
  for (int nt = 0; nt < 8; ++nt) acc0[nt] = (f32x4){0.f, 0.f, 0.f, 0.f};
#pragma unroll
  for (int ks = 0; ks < 4; ++ks) {
    int chA = (ks << 2) + kg;
    f16x8 afrag = *(const f16x8*)&sA[arow * 64 + ((chA ^ (arow & 15)) << 2)];
#pragma unroll
    for (int nt = 0; nt < 8; ++nt) {
      int col = (nt << 4) + cl;
      f16x8 b0 = *(const f16x8*)&sB0[col * 64 + ((chA ^ (col & 15)) << 2)];
      acc0[nt] = __builtin_amdgcn_mfma_f32_16x16x32_f16(afrag, b0, acc0[nt], 0, 0, 0);
    }
  }
  int rbase = (wid << 4) + (kg << 2);
#pragma unroll
  for (int nt = 0; nt < 8; ++nt) {
#pragma unroll
    for (int r = 0; r < 4; ++r) {
      int row = rbase + r;
      if (row < rows)
        C0[(size_t)(bm + row) * DIM + (nt << 4) + cl] = f16rn(acc0[nt][r] * scale0);
    }
  }
  if (!isH) {
    for (int ch = t; ch < 64 * 16; ch += 256) {
      int r = ch >> 4, c0 = ch & 15;
      if (r < rows) {
        uint4 v = *(uint4*)&sA[r * 64 + ((c0 ^ (r & 15)) << 2)];
        *(uint4*)(ne_h + (size_t)(bm + r) * DIM + c0 * 8) = v;
      }
    }
  }
}

// bucket scatter, 4 edges/thread via 3x int4 loads
__global__ __launch_bounds__(256) void k_scatter(const int* __restrict__ sl,
                                                 int* __restrict__ cnt,
                                                 uint* __restrict__ ed) {
  int i = blockIdx.x * 256 + threadIdx.x;
  int e0 = i * 4;
  if (e0 >= N_EDGES_C) return;
  const int4* p = (const int4*)(sl + 3 * e0);
  int4 a = p[0], b = p[1], c = p[2];
  int nd[4] = {a.x, a.w, b.z, c.y};
  int hh[4] = {a.y, b.x, b.w, c.z};
  int rl[4] = {a.z, b.y, c.x, c.w};
#pragma unroll
  for (int j = 0; j < 4; ++j) {
    int pos = atomicAdd(&cnt[hh[j]], 1);
    if (pos < CAP) ed[(size_t)hh[j] * CAP + pos] = (uint)nd[j] | ((uint)rl[j] << 16);
  }
}

// one wave per hyperedge (2/block); 8 groups x 8 lanes. All q-words bulk-
// preloaded into 2 regs (coalesced), rounds uniform, 1-deep predicated row
// prefetch. fp16 gathers, f32 accum, no softmax-max. Output fp16.
#define NG 8
#define BLK_H 2
__global__ __launch_bounds__(128) void k_agg(
    const ushort* __restrict__ rh_h, const ushort* __restrict__ rt_h,
    const ushort* __restrict__ semt_h, const ushort* __restrict__ ne_h,
    const uint* __restrict__ ed, const int* __restrict__ cnt,
    ushort* __restrict__ agg_h) {
  int wave = threadIdx.x >> 6;
  int lane = threadIdx.x & 63;
  int h = blockIdx.x * BLK_H + wave;
  int g = lane >> 3;
  int pos = lane & 7;
  int d0 = pos * 16;
  const uint4* tp = (const uint4*)(rt_h + ((size_t)h << 7) + d0);
  uint4 tba = tp[0], tbb = tp[1];
  __half2 tb0 = u2h2(tba.x), tb1 = u2h2(tba.y), tb2 = u2h2(tba.z), tb3 = u2h2(tba.w);
  __half2 tb4 = u2h2(tbb.x), tb5 = u2h2(tbb.y), tb6 = u2h2(tbb.z), tb7 = u2h2(tbb.w);
  const __half2 one2 = __floats2half2_rn(1.0f, 1.0f);
  const __half2 m2 = __floats2half2_rn(-2.0f, -2.0f);
  size_t base = (size_t)h * CAP;
  int n = min(cnt[h], CAP);
  // bulk q preload: 2 coalesced loads cover all <=128 bucket entries
  uint qv0 = (lane < n) ? ed[base + lane] : 0u;
  uint qv1 = (64 + lane < n) ? ed[base + 64 + lane] : 0u;
  int rounds = (n + NG - 1) / NG;
  float l = 0.0f;
  float4 a0 = {0,0,0,0}, a1 = {0,0,0,0}, a2 = {0,0,0,0}, a3 = {0,0,0,0};
  uint4 ha, hb, sa, sb, na, nb;
  if (rounds > 0) {
    uint q = getq(qv0, qv1, g);
    int node = (int)(q & 0xffffu), rel = (int)(q >> 16);
    const uint4* hp = (const uint4*)(rh_h + ((size_t)node << 7) + d0);
    const uint4* sp = (const uint4*)(semt_h + ((size_t)rel << 7) + d0);
    const uint4* np = (const uint4*)(ne_h + ((size_t)node << 7) + d0);
    ha = hp[0]; hb = hp[1]; sa = sp[0]; sb = sp[1]; na = np[0]; nb = np[1];
  }
  for (int r = 0; r < rounds; ++r) {
    uint4 pha, phb, psa, psb, pna, pnb;
    bool pf = (r + 1) < rounds;
    if (pf) {
      uint qn = getq(qv0, qv1, (r + 1) * NG + g);
      int node = (int)(qn & 0xffffu), rel = (int)(qn >> 16);
      const uint4* hp = (const uint4*)(rh_h + ((size_t)node << 7) + d0);
      const uint4* sp = (const uint4*)(semt_h + ((size_t)rel << 7) + d0);
      const uint4* np = (const uint4*)(ne_h + ((size_t)node << 7) + d0);
      pha = hp[0]; phb = hp[1]; psa = sp[0]; psb = sp[1]; pna = np[0]; pnb = np[1];
    }
    float da = 0.0f, db = 0.0f;
#define TP(US, UH, TB, ACC)                      \
    {                                            \
      __half2 arg = __hadd2(TB, u2h2(US));       \
      __half2 e2v = h2exp2(arg);                 \
      __half2 r2 = h2rcp(__hadd2(e2v, one2));    \
      __half2 t2 = __hfma2(m2, r2, one2);        \
      ACC = fdot2(u2h2(UH), t2, ACC);            \
    }
    TP(sa.x, ha.x, tb0, da) TP(sa.y, ha.y, tb1, db)
    TP(sa.z, ha.z, tb2, da) TP(sa.w, ha.w, tb3, db)
    TP(sb.x, hb.x, tb4, da) TP(sb.y, hb.y, tb5, db)
    TP(sb.z, hb.z, tb6, da) TP(sb.w, hb.w, tb7, db)
#undef TP
    float dot = da + db;   // = score * log2e (rh prescaled)
    dot += __shfl_xor(dot, 1, 64);
    dot += __shfl_xor(dot, 2, 64);
    dot += __shfl_xor(dot, 4, 64);
    float p = (g + r * NG < n) ? exp2f(dot) : 0.0f;
    l += p;
    float2 n0 = __half22float2(u2h2(na.x));
    float2 n1 = __half22float2(u2h2(na.y));
    float2 n2 = __half22float2(u2h2(na.z));
    float2 n3 = __half22float2(u2h2(na.w));
    float2 n4 = __half22float2(u2h2(nb.x));
    float2 n5 = __half22float2(u2h2(nb.y));
    float2 n6 = __half22float2(u2h2(nb.z));
    float2 n7 = __half22float2(u2h2(nb.w));
    a0.x = fmaf(p, n0.x, a0.x); a0.y = fmaf(p, n0.y, a0.y);
    a0.z = fmaf(p, n1.x, a0.z); a0.w = fmaf(p, n1.y, a0.w);
    a1.x = fmaf(p, n2.x, a1.x); a1.y = fmaf(p, n2.y, a1.y);
    a1.z = fmaf(p, n3.x, a1.z); a1.w = fmaf(p, n3.y, a1.w);
    a2.x = fmaf(p, n4.x, a2.x); a2.y = fmaf(p, n4.y, a2.y);
    a2.z = fmaf(p, n5.x, a2.z); a2.w = fmaf(p, n5.y, a2.w);
    a3.x = fmaf(p, n6.x, a3.x); a3.y = fmaf(p, n6.y, a3.y);
    a3.z = fmaf(p, n7.x, a3.z); a3.w = fmaf(p, n7.y, a3.w);
    if (pf) { ha = pha; hb = phb; sa = psa; sb = psb; na = pna; nb = pnb; }
  }
#pragma unroll
  for (int mo = 8; mo < 64; mo <<= 1) {
    l += __shfl_xor(l, mo, 64);
    a0.x += __shfl_xor(a0.x, mo, 64); a0.y += __shfl_xor(a0.y, mo, 64);
    a0.z += __shfl_xor(a0.z, mo, 64); a0.w += __shfl_xor(a0.w, mo, 64);
    a1.x += __shfl_xor(a1.x, mo, 64); a1.y += __shfl_xor(a1.y, mo, 64);
    a1.z += __shfl_xor(a1.z, mo, 64); a1.w += __shfl_xor(a1.w, mo, 64);
    a2.x += __shfl_xor(a2.x, mo, 64); a2.y += __shfl_xor(a2.y, mo, 64);
    a2.z += __shfl_xor(a2.z, mo, 64); a2.w += __shfl_xor(a2.w, mo, 64);
    a3.x += __shfl_xor(a3.x, mo, 64); a3.y += __shfl_xor(a3.y, mo, 64);
    a3.z += __shfl_xor(a3.z, mo, 64); a3.w += __shfl_xor(a3.w, mo, 64);
  }
  if (g == 0) {
    float inv = (l > 0.0f) ? __builtin_amdgcn_rcpf(l) : 0.0f;
    uint4 w0, w1;
    w0.x = (uint)f16rn(a0.x * inv) | ((uint)f16rn(a0.y * inv) << 16);
    w0.y = (uint)f16rn(a0.z * inv) | ((uint)f16rn(a0.w * inv) << 16);
    w0.z = (uint)f16rn(a1.x * inv) | ((uint)f16rn(a1.y * inv) << 16);
    w0.w = (uint)f16rn(a1.z * inv) | ((uint)f16rn(a1.w * inv) << 16);
    w1.x = (uint)f16rn(a2.x * inv) | ((uint)f16rn(a2.y * inv) << 16);
    w1.y = (uint)f16rn(a2.z * inv) | ((uint)f16rn(a2.w * inv) << 16);
    w1.z = (uint)f16rn(a3.x * inv) | ((uint)f16rn(a3.y * inv) << 16);
    w1.w = (uint)f16rn(a3.z * inv) | ((uint)f16rn(a3.w * inv) << 16);
    *(uint4*)(agg_h + ((size_t)h << 7) + d0) = w0;
    *(uint4*)(agg_h + ((size_t)h << 7) + d0 + 8) = w1;
  }
}

// final: C = agg @ lin_w.T (MFMA fp16), fused bias+LeakyReLU+LayerNorm epilogue
__global__ __launch_bounds__(256) void k_mfma_ln(
    const ushort* __restrict__ Ah, const ushort* __restrict__ LWh,
    const float* __restrict__ bias, const float* __restrict__ gamma,
    const float* __restrict__ beta, float* __restrict__ out, int M) {
  __shared__ uint sA[64 * 64];
  __shared__ uint sB0[128 * 64];
  int t = threadIdx.x;
  int bm = blockIdx.x * 64;
  int rows = min(64, M - bm);
  for (int ch = t; ch < 64 * 16; ch += 256) {
    int r = ch >> 4, c0 = ch & 15;
    uint4 v = {0u, 0u, 0u, 0u};
    if (r < rows) v = *(const uint4*)(Ah + (size_t)(bm + r) * DIM + c0 * 8);
    *(uint4*)&sA[r * 64 + ((c0 ^ (r & 15)) << 2)] = v;
  }
  for (int ch = t; ch < 128 * 16; ch += 256) {
    int c = ch >> 4, c0 = ch & 15;
    uint4 v = *(const uint4*)(LWh + c * DIM + c0 * 8);
    *(uint4*)&sB0[c * 64 + ((c0 ^ (c & 15)) << 2)] = v;
  }
  __syncthreads();
  int wid = t >> 6, lane = t & 63;
  int arow = (wid << 4) + (lane & 15);
  int kg = lane >> 4;
  int cl = lane & 15;
  f32x4 acc0[8];
#pragma unroll
  for (int nt = 0; nt < 8; ++nt) acc0[nt] = (f32x4){0.f, 0.f, 0.f, 0.f};
#pragma unroll
  for (int ks = 0; ks < 4; ++ks) {
    int chA = (ks << 2) + kg;
    f16x8 afrag = *(const f16x8*)&sA[arow * 64 + ((chA ^ (arow & 15)) << 2)];
#pragma unroll
    for (int nt = 0; nt < 8; ++nt) {
      int col = (nt << 4) + cl;
      f16x8 b0 = *(const f16x8*)&sB0[col * 64 + ((chA ^ (col & 15)) << 2)];
      acc0[nt] = __builtin_amdgcn_mfma_f32_16x16x32_f16(afrag, b0, acc0[nt], 0, 0, 0);
    }
  }
  float bv[8], gv[8], ev[8];
#pragma unroll
  for (int nt = 0; nt < 8; ++nt) {
    int col = (nt << 4) + cl;
    bv[nt] = bias[col]; gv[nt] = gamma[col]; ev[nt] = beta[col];
  }
  int rbase = (wid << 4) + (kg << 2);
#pragma unroll
  for (int r = 0; r < 4; ++r) {
    float s = 0.f, q = 0.f;
#pragma unroll
    for (int nt = 0; nt < 8; ++nt) {
      float x = acc0[nt][r] + bv[nt];
      x = x >= 0.0f ? x : 0.01f * x;
      acc0[nt][r] = x;
      s += x; q += x * x;
    }
#pragma unroll
    for (int mo = 1; mo < 16; mo <<= 1) {
      s += __shfl_xor(s, mo, 64);
      q += __shfl_xor(q, mo, 64);
    }
    float mu = s * (1.0f / 128.0f);
    float var = q * (1.0f / 128.0f) - mu * mu;
    float inv = rsqrtf(var + 1e-5f);
    int row = rbase + r;
    if (row < rows) {
      float* Or = out + (size_t)(bm + row) * DIM;
#pragma unroll
      for (int nt = 0; nt < 8; ++nt)
        Or[(nt << 4) + cl] = (acc0[nt][r] - mu) * inv * gv[nt] + ev[nt];
    }
  }
}

extern "C" void kernel_launch(void* const* d_in, const int* in_sizes, int n_in,
                              void* d_out, int out_size, void* d_ws, size_t ws_size,
                              hipStream_t stream) {
  const float* node_emb = (const float*)d_in[0];
  const float* sem_emb = (const float*)d_in[1];
  const float* hyper_emb = (const float*)d_in[2];
  const float* W_r = (const float*)d_in[3];
  const float* lin_w = (const float*)d_in[4];
  const float* lin_b = (const float*)d_in[5];
  const float* sem_w = (const float*)d_in[6];
  const float* sem_b = (const float*)d_in[7];
  const float* ln_g = (const float*)d_in[8];
  const float* ln_b = (const float*)d_in[9];
  const int* sl = (const int*)d_in[10];
  float* out = (float*)d_out;

  // all segments 256-byte aligned
  char* ws = (char*)d_ws;
  ushort* agg_h = (ushort*)ws;                    // 2,560,000 halfs
  int* cnt = (int*)(ws + 5120000);                // 20,480 ints
  uint* ed = (uint*)(ws + 5201920);               // 2,560,000 u32
  ushort* rt_h = (ushort*)(ws + 15441920);        // 2,560,000 halfs
  ushort* rh_h = (ushort*)(ws + 20561920);        // 6,400,000 halfs
  ushort* ne_h = (ushort*)(ws + 33361920);        // 6,400,000 halfs
  ushort* semt_h = (ushort*)(ws + 46161920);      // 32,768 halfs
  ushort* WT_h = (ushort*)(ws + 46227456);        // 16,384 halfs
  ushort* LW_h = (ushort*)(ws + 46260224);        // 16,384 halfs

  const int HB = (N_HYPER + 63) / 64;
  const int NB = (N_NODES + 63) / 64;
  hipMemsetAsync(cnt, 0, sizeof(int) * 20480, stream);
  k_pre<<<N_REL + 256, 128, 0, stream>>>(sem_emb, sem_w, sem_b, semt_h,
                                         W_r, lin_w, WT_h, LW_h);
  k_scatter<<<(N_EDGES_C / 4 + 255) / 256, 256, 0, stream>>>(sl, cnt, ed);
  k_mfma_all<<<HB + NB, 256, 0, stream>>>(hyper_emb, node_emb, WT_h,
                                          rt_h, rh_h, ne_h);
  k_agg<<<N_HYPER / BLK_H, 128, 0, stream>>>(rh_h, rt_h, semt_h, ne_h, ed, cnt, agg_h);
  k_mfma_ln<<<HB, 256, 0, stream>>>(agg_h, LW_h, lin_b, ln_g, ln_b, out, N_HYPER);
}